// Round 1
// baseline (295.946 us; speedup 1.0000x reference)
//
#include <hip/hip_runtime.h>
#include <math.h>

// Problem constants (B=128, S=4096, M=20)
#define BB 128
#define SS 4096
#define MM 20
#define NPOS (BB * SS)          // 524288
#define BLOCK 256
#define NBLOCKS (NPOS / BLOCK)  // 2048

__device__ __forceinline__ float fast_rcp(float x) { return __builtin_amdgcn_rcpf(x); }

__global__ __launch_bounds__(BLOCK) void sketch_main(
    const float* __restrict__ xs,        // (B,S,5)
    const float* __restrict__ logits,    // (B,S,20)
    const float* __restrict__ mus,       // (B,S,20,2)
    const float* __restrict__ sigmas,    // (B,S,20,3)
    const float* __restrict__ pen_pred,  // (B,S,3)
    float* __restrict__ partials)        // (NBLOCKS)
{
    const float LOG_2PI = 1.8378770664093453f;
    int idx = blockIdx.x * BLOCK + threadIdx.x;   // position index in [0, NPOS)
    int s = idx & (SS - 1);

    // ---- xs: current position, pen_true, previous position ----
    const float* xp = xs + (size_t)idx * 5;
    float px  = xp[0], py  = xp[1];
    float pt0 = xp[2], pt1 = xp[3], pt2 = xp[4];
    float qx = 0.0f, qy = 0.0f;
    if (s != 0) { qx = xp[-5]; qy = xp[-4]; }
    float rx = px - qx, ry = py - qy;

    // ---- vectorized loads: logits (5x f4), mus (10x f4), sigmas (15x f4) ----
    const float4* lp = (const float4*)(logits + (size_t)idx * 20);
    float lg[20];
#pragma unroll
    for (int i = 0; i < 5; ++i) {
        float4 v = lp[i];
        lg[4*i+0]=v.x; lg[4*i+1]=v.y; lg[4*i+2]=v.z; lg[4*i+3]=v.w;
    }
    const float4* mp = (const float4*)(mus + (size_t)idx * 40);
    float mu[40];
#pragma unroll
    for (int i = 0; i < 10; ++i) {
        float4 v = mp[i];
        mu[4*i+0]=v.x; mu[4*i+1]=v.y; mu[4*i+2]=v.z; mu[4*i+3]=v.w;
    }
    const float4* sp = (const float4*)(sigmas + (size_t)idx * 60);
    float sg[60];
#pragma unroll
    for (int i = 0; i < 15; ++i) {
        float4 v = sp[i];
        sg[4*i+0]=v.x; sg[4*i+1]=v.y; sg[4*i+2]=v.z; sg[4*i+3]=v.w;
    }

    // ---- mixture component log-probs; track maxes for the two logsumexps ----
    float a[20];
    float mx_l = -INFINITY, mx_a = -INFINITY;
#pragma unroll
    for (int m = 0; m < MM; ++m) {
        float l00 = sg[3*m+0], l10 = sg[3*m+1], l11 = sg[3*m+2];
        float dx = rx - mu[2*m+0];
        float dy = ry - mu[2*m+1];
        float z0 = dx * fast_rcp(l00);
        float z1 = (dy - l10 * z0) * fast_rcp(l11);
        // -log(l00) - log(l11) == -log(l00*l11): one transcendental instead of two
        float comp = -0.5f * (z0*z0 + z1*z1) - LOG_2PI - __logf(l00 * l11);
        float av = lg[m] + comp;
        a[m] = av;
        mx_l = fmaxf(mx_l, lg[m]);
        mx_a = fmaxf(mx_a, av);
    }
    float se_l = 0.0f, se_a = 0.0f;
#pragma unroll
    for (int m = 0; m < MM; ++m) {
        se_l += __expf(lg[m] - mx_l);
        se_a += __expf(a[m]  - mx_a);
    }
    // mix_logp = lse(logits + comp) - lse(logits)
    float mix_logp = (mx_a + __logf(se_a)) - (mx_l + __logf(se_l));

    // ---- pen term: -sum(pen_pred * log_softmax(pen_true)) / NPOS ----
    float pm = fmaxf(pt0, fmaxf(pt1, pt2));
    float es = __expf(pt0 - pm) + __expf(pt1 - pm) + __expf(pt2 - pm);
    float lse3 = pm + __logf(es);
    const float* pp = pen_pred + (size_t)idx * 3;
    float pen = -(pp[0]*(pt0-lse3) + pp[1]*(pt1-lse3) + pp[2]*(pt2-lse3));

    float val = -mix_logp + pen * (1.0f / (float)NPOS);

    // ---- block reduction: wave shuffle -> LDS -> one partial per block ----
#pragma unroll
    for (int off = 32; off > 0; off >>= 1) val += __shfl_down(val, off, 64);
    __shared__ float red[BLOCK / 64];
    int lane = threadIdx.x & 63, wid = threadIdx.x >> 6;
    if (lane == 0) red[wid] = val;
    __syncthreads();
    if (threadIdx.x == 0)
        partials[blockIdx.x] = red[0] + red[1] + red[2] + red[3];
}

__global__ __launch_bounds__(BLOCK) void sketch_reduce(
    const float* __restrict__ partials, float* __restrict__ out)
{
    float v = 0.0f;
    for (int i = threadIdx.x; i < NBLOCKS; i += BLOCK) v += partials[i];
#pragma unroll
    for (int off = 32; off > 0; off >>= 1) v += __shfl_down(v, off, 64);
    __shared__ float red[BLOCK / 64];
    int lane = threadIdx.x & 63, wid = threadIdx.x >> 6;
    if (lane == 0) red[wid] = v;
    __syncthreads();
    if (threadIdx.x == 0)
        out[0] = red[0] + red[1] + red[2] + red[3];
}

extern "C" void kernel_launch(void* const* d_in, const int* in_sizes, int n_in,
                              void* d_out, int out_size, void* d_ws, size_t ws_size,
                              hipStream_t stream) {
    const float* xs       = (const float*)d_in[0];
    const float* logits   = (const float*)d_in[1];
    const float* mus      = (const float*)d_in[2];
    const float* sigmas   = (const float*)d_in[3];
    const float* pen_pred = (const float*)d_in[4];
    float* out = (float*)d_out;
    float* partials = (float*)d_ws;   // NBLOCKS floats = 8 KB

    sketch_main<<<NBLOCKS, BLOCK, 0, stream>>>(xs, logits, mus, sigmas, pen_pred, partials);
    sketch_reduce<<<1, BLOCK, 0, stream>>>(partials, out);
}